// Round 1
// baseline (289.704 us; speedup 1.0000x reference)
//
#include <hip/hip_runtime.h>
#include <hip/hip_bf16.h>

// Problem constants (from reference setup_inputs)
#define BB 4
#define MM 16384
#define NN 32768
#define KK 16
#define ROWS (BB * NN)   // 131072
#define OUTW 131         // 3 coords + 64 + 64
#define RPW 32           // rows per wave in the proj kernels
#define A_BLOCKS (ROWS / (RPW * 4))  // 1024 blocks of 4 waves

// ---------------------------------------------------------------------------
// Kernel 1: gather + max-pool + (pooled @ W1 + b1) -> out[..., 3:67]
//           also writes skip_coords -> out[..., 0:3]
//           accumulates per-channel sum / sumsq into ws[0:64] / ws[64:128]
// One wave (64 lanes) per row; lane = channel. W1 column held in registers.
// ---------------------------------------------------------------------------
__global__ __launch_bounds__(256) void k_pool_proj(
    const float* __restrict__ cf, const int* __restrict__ idxs,
    const float* __restrict__ scoord,
    const float* __restrict__ W1, const float* __restrict__ b1,
    float* __restrict__ out, float* __restrict__ acc)
{
    __shared__ float pool[4][64];
    __shared__ float lsum[64], lsq[64];
    const int lane = threadIdx.x & 63;
    const int wv   = threadIdx.x >> 6;
    if (threadIdx.x < 64) { lsum[threadIdx.x] = 0.f; lsq[threadIdx.x] = 0.f; }
    __syncthreads();

    // W1 column for output channel `lane` in registers (64 VGPRs)
    float w[64];
#pragma unroll
    for (int c = 0; c < 64; ++c) w[c] = W1[c * 64 + lane];
    const float bias = b1[lane];

    float psum = 0.f, psq = 0.f;
    const int gw = blockIdx.x * 4 + wv;
    for (int r0 = 0; r0 < RPW; ++r0) {
        const int r = gw * RPW + r0;
        const int b = r >> 15;            // N = 32768 = 2^15
        int mi = 0;
        if (lane < KK) mi = idxs[r * KK + lane];
        float pmax = -3.402823466e38f;
#pragma unroll
        for (int k = 0; k < KK; ++k) {
            const int m = __shfl(mi, k);
            pmax = fmaxf(pmax, cf[(((b << 14) + m) << 6) + lane]);
        }
        pool[wv][lane] = pmax;                   // wave-private tile; LDS ops
        __builtin_amdgcn_wave_barrier();         // in-order within a wave

        float y = bias;
#pragma unroll
        for (int c = 0; c < 64; ++c) y = fmaf(pool[wv][c], w[c], y);
        __builtin_amdgcn_wave_barrier();

        const size_t ob = (size_t)r * OUTW;
        out[ob + 3 + lane] = y;
        if (lane < 3) out[ob + lane] = scoord[r * 3 + lane];
        psum += y; psq += y * y;
    }
    atomicAdd(&lsum[lane], psum);
    atomicAdd(&lsq[lane], psq);
    __syncthreads();
    if (threadIdx.x < 64) {
        atomicAdd(&acc[threadIdx.x],      lsum[threadIdx.x]);
        atomicAdd(&acc[64 + threadIdx.x], lsq[threadIdx.x]);
    }
}

// ---------------------------------------------------------------------------
// Kernel 2: (skip_feat @ W2 + b2) -> out[..., 67:131]
//           accumulates per-channel sum / sumsq into ws[128:192] / ws[192:256]
// ---------------------------------------------------------------------------
__global__ __launch_bounds__(256) void k_skip_proj(
    const float* __restrict__ sf,
    const float* __restrict__ W2, const float* __restrict__ b2,
    float* __restrict__ out, float* __restrict__ acc)
{
    __shared__ float srow[4][64];
    __shared__ float lsum[64], lsq[64];
    const int lane = threadIdx.x & 63;
    const int wv   = threadIdx.x >> 6;
    if (threadIdx.x < 64) { lsum[threadIdx.x] = 0.f; lsq[threadIdx.x] = 0.f; }
    __syncthreads();

    float w[64];
#pragma unroll
    for (int c = 0; c < 64; ++c) w[c] = W2[c * 64 + lane];
    const float bias = b2[lane];

    float psum = 0.f, psq = 0.f;
    const int gw = blockIdx.x * 4 + wv;
    for (int r0 = 0; r0 < RPW; ++r0) {
        const int r = gw * RPW + r0;
        srow[wv][lane] = sf[(size_t)r * 64 + lane];
        __builtin_amdgcn_wave_barrier();

        float y = bias;
#pragma unroll
        for (int c = 0; c < 64; ++c) y = fmaf(srow[wv][c], w[c], y);
        __builtin_amdgcn_wave_barrier();

        const size_t ob = (size_t)r * OUTW;
        out[ob + 67 + lane] = y;
        psum += y; psq += y * y;
    }
    atomicAdd(&lsum[lane], psum);
    atomicAdd(&lsq[lane], psq);
    __syncthreads();
    if (threadIdx.x < 64) {
        atomicAdd(&acc[128 + threadIdx.x], lsum[threadIdx.x]);
        atomicAdd(&acc[192 + threadIdx.x], lsq[threadIdx.x]);
    }
}

// ---------------------------------------------------------------------------
// Kernel 3: fold sums -> affine params  a = g*rsqrt(var+eps), c = beta - mu*a
// ws layout: [0:64] sum1 [64:128] sq1 [128:192] sum2 [192:256] sq2
//            [256:384] a (a1|a2)  [384:512] c (c1|c2)
// ---------------------------------------------------------------------------
__global__ void k_stats(float* __restrict__ ws,
                        const float* __restrict__ g1, const float* __restrict__ be1,
                        const float* __restrict__ g2, const float* __restrict__ be2)
{
    const int o = threadIdx.x;  // 64 threads
    const float inv = 1.0f / (float)ROWS;
    float m1 = ws[o] * inv;
    float v1 = ws[64 + o] * inv - m1 * m1;
    float a1 = g1[o] * rsqrtf(v1 + 1e-5f);
    ws[256 + o] = a1;
    ws[384 + o] = be1[o] - m1 * a1;
    float m2 = ws[128 + o] * inv;
    float v2 = ws[192 + o] * inv - m2 * m2;
    float a2 = g2[o] * rsqrtf(v2 + 1e-5f);
    ws[256 + 64 + o] = a2;
    ws[384 + 64 + o] = be2[o] - m2 * a2;
}

// ---------------------------------------------------------------------------
// Kernel 4: in-place  out[r*131 + 3 + j] = relu(a[j]*y + c[j]),  j in [0,128)
// ---------------------------------------------------------------------------
__global__ __launch_bounds__(256) void k_finalize(float* __restrict__ out,
                                                  const float* __restrict__ ws)
{
    const size_t T  = (size_t)gridDim.x * blockDim.x;
    const size_t t0 = (size_t)blockIdx.x * blockDim.x + threadIdx.x;
#pragma unroll
    for (int i = 0; i < 4; ++i) {
        const size_t e = t0 + (size_t)i * T;       // e < ROWS*128
        const size_t r = e >> 7;
        const int    j = (int)(e & 127);
        const size_t ad = r * OUTW + 3 + j;
        const float v = out[ad];
        out[ad] = fmaxf(fmaf(v, ws[256 + j], ws[384 + j]), 0.f);
    }
}

// ---------------------------------------------------------------------------
extern "C" void kernel_launch(void* const* d_in, const int* in_sizes, int n_in,
                              void* d_out, int out_size, void* d_ws, size_t ws_size,
                              hipStream_t stream)
{
    const float* cf     = (const float*)d_in[1];   // curr_feat (B,M,64)
    const float* scoord = (const float*)d_in[2];   // skip_coords (B,N,3)
    const float* sf     = (const float*)d_in[3];   // skip_feat (B,N,64)
    const int*   idxs   = (const int*)  d_in[4];   // upsampling_idxs (B,N,16)
    const float* W1     = (const float*)d_in[5];
    const float* b1     = (const float*)d_in[6];
    const float* g1     = (const float*)d_in[7];
    const float* be1    = (const float*)d_in[8];
    const float* W2     = (const float*)d_in[9];
    const float* b2     = (const float*)d_in[10];
    const float* g2     = (const float*)d_in[11];
    const float* be2    = (const float*)d_in[12];
    float* out = (float*)d_out;
    float* ws  = (float*)d_ws;

    hipMemsetAsync(ws, 0, 256 * sizeof(float), stream);  // zero the accumulators
    k_pool_proj<<<A_BLOCKS, 256, 0, stream>>>(cf, idxs, scoord, W1, b1, out, ws);
    k_skip_proj<<<A_BLOCKS, 256, 0, stream>>>(sf, W2, b2, out, ws);
    k_stats<<<1, 64, 0, stream>>>(ws, g1, be1, g2, be2);
    // ROWS*128 = 16,777,216 elements; 16384 blocks * 256 threads * 4 elems
    k_finalize<<<16384, 256, 0, stream>>>(out, ws);
}